// Round 10
// baseline (681.032 us; speedup 1.0000x reference)
//
#include <hip/hip_runtime.h>

#define NU 200000
#define NM 100000
#define NE 4000000
#define D  64

#define BDST 128                           // destinations per bucket (dst >> 7)
#define BU_BKTS ((NU + BDST - 1) / BDST)   // 1563 user buckets
#define BM_BKTS ((NM + BDST - 1) / BDST)   // 782 movie buckets
#define NBKT (BU_BKTS + BM_BKTS)           // 2345
#define NBLK 256                           // partition blocking
#define CHUNK ((NE + NBLK - 1) / NBLK)     // 15625

typedef unsigned int uint_t;
typedef unsigned short ushort_t;
typedef unsigned char uchar_t;
typedef __attribute__((ext_vector_type(8))) short short8_t;   // 8 bf16 (4 VGPR)
typedef __attribute__((ext_vector_type(4))) float f32x4_t;    // MFMA acc

__device__ __forceinline__ ushort_t f2bf(float f) {            // RNE f32->bf16
  uint_t u = __float_as_uint(f);
  return (ushort_t)((u + 0x7FFFu + ((u >> 16) & 1u)) >> 16);
}
__device__ __forceinline__ float bflo(uint_t p) { return __uint_as_float(p << 16); }
__device__ __forceinline__ float bfhi(uint_t p) { return __uint_as_float(p & 0xFFFF0000u); }

// ---------------------------------------------------------------------------
// cast x_user / x_movie to bf16 (vectorized float4 -> ushort4)
// ---------------------------------------------------------------------------
__global__ __launch_bounds__(256) void cast_k(const float* __restrict__ xu,
                                              const float* __restrict__ xm,
                                              ushort_t* __restrict__ xu_h,
                                              ushort_t* __restrict__ xm_h) {
  const int n_u = NU * D / 4, n_m = NM * D / 4;
  const int stride = gridDim.x * blockDim.x;
  for (int i = blockIdx.x * blockDim.x + threadIdx.x; i < n_u + n_m; i += stride) {
    const bool isu = (i < n_u);
    const float4 v = isu ? ((const float4*)xu)[i] : ((const float4*)xm)[i - n_u];
    ushort4 o;
    o.x = f2bf(v.x); o.y = f2bf(v.y); o.z = f2bf(v.z); o.w = f2bf(v.w);
    if (isu) ((ushort4*)xu_h)[i] = o;
    else     ((ushort4*)xm_h)[i - n_u] = o;
  }
}

// ---------------------------------------------------------------------------
// weight prep: swizzle 8 f32 64x64 matrices into per-lane MFMA B-fragments.
// frag[mat][t][h][lane][j] = bf16( W[h*32 + (lane>>4)*8 + j][t*16 + (lane&15)] )
// ---------------------------------------------------------------------------
__global__ __launch_bounds__(256) void wprep_k(
    const float* __restrict__ W0, const float* __restrict__ W1,
    const float* __restrict__ W2, const float* __restrict__ W3,
    const float* __restrict__ W4, const float* __restrict__ W5,
    const float* __restrict__ W6, const float* __restrict__ W7,
    ushort_t* __restrict__ frag) {
  const int idx = blockIdx.x * 256 + threadIdx.x;   // 8 mats * 512 entries
  if (idx >= 8 * 512) return;
  const int lane = idx & 63;
  const int h = (idx >> 6) & 1;
  const int t = (idx >> 7) & 3;
  const int mat = idx >> 9;
  const float* W = mat == 0 ? W0 : mat == 1 ? W1 : mat == 2 ? W2 : mat == 3 ? W3
                 : mat == 4 ? W4 : mat == 5 ? W5 : mat == 6 ? W6 : W7;
  const int col = t * 16 + (lane & 15);
  const int kb = h * 32 + (lane >> 4) * 8;
#pragma unroll
  for (int j = 0; j < 8; ++j)
    frag[(size_t)idx * 8 + j] = f2bf(W[(kb + j) * D + col]);
}

// ---------------------------------------------------------------------------
// K1: per-block bucket histogram (both directions), LDS atomics only.
// ---------------------------------------------------------------------------
__global__ __launch_bounds__(256) void hist_k(const int* __restrict__ uidx,
                                              const int* __restrict__ midx,
                                              int* __restrict__ C_u,
                                              int* __restrict__ C_m) {
  __shared__ int h[NBKT];
  for (int i = threadIdx.x; i < NBKT; i += 256) h[i] = 0;
  __syncthreads();
  const int base = blockIdx.x * CHUNK;
  const int lim = min(base + CHUNK, NE);
  for (int e = base + threadIdx.x; e < lim; e += 256) {
    atomicAdd(&h[uidx[e] >> 7], 1);
    atomicAdd(&h[BU_BKTS + (midx[e] >> 7)], 1);
  }
  __syncthreads();
  for (int i = threadIdx.x; i < BU_BKTS; i += 256) C_u[(size_t)blockIdx.x * BU_BKTS + i] = h[i];
  for (int i = threadIdx.x; i < BM_BKTS; i += 256) C_m[(size_t)blockIdx.x * BM_BKTS + i] = h[BU_BKTS + i];
}

// ---------------------------------------------------------------------------
// K2a: per-bucket exclusive prefix over the 256 blocks; emit bucket totals.
// ---------------------------------------------------------------------------
__global__ __launch_bounds__(256) void colscan_k(int* __restrict__ C_u,
                                                 int* __restrict__ C_m,
                                                 int* __restrict__ tot_u,
                                                 int* __restrict__ tot_m) {
  const int t = blockIdx.x * blockDim.x + threadIdx.x;
  if (t < BU_BKTS) {
    int run = 0;
    for (int blk = 0; blk < NBLK; ++blk) {
      const size_t idx = (size_t)blk * BU_BKTS + t;
      const int v = C_u[idx];
      C_u[idx] = run;
      run += v;
    }
    tot_u[t] = run;
  } else if (t < NBKT) {
    const int b = t - BU_BKTS;
    int run = 0;
    for (int blk = 0; blk < NBLK; ++blk) {
      const size_t idx = (size_t)blk * BM_BKTS + b;
      const int v = C_m[idx];
      C_m[idx] = run;
      run += v;
    }
    tot_m[b] = run;
  }
}

// ---------------------------------------------------------------------------
// K2b: single-block exclusive scans of bucket totals -> bucket bases.
// ---------------------------------------------------------------------------
__device__ void scan_inline(const int* __restrict__ in, int* __restrict__ out,
                            int n, int* partial) {
  const int tid = threadIdx.x;
  const int chunk = (n + 1023) / 1024;
  const int s = tid * chunk;
  const int e = min(s + chunk, n);
  int sum = 0;
  for (int i = s; i < e; ++i) sum += in[i];
  partial[tid] = sum;
  __syncthreads();
  for (int off = 1; off < 1024; off <<= 1) {
    int v = (tid >= off) ? partial[tid - off] : 0;
    __syncthreads();
    if (tid >= off) partial[tid] += v;
    __syncthreads();
  }
  int run = (tid == 0) ? 0 : partial[tid - 1];
  for (int i = s; i < e; ++i) {
    out[i] = run;
    run += in[i];
  }
  if (tid == 1023) out[n] = partial[1023];
}

__global__ __launch_bounds__(1024) void bucketscan_k(const int* __restrict__ tot_u,
                                                     int* __restrict__ bb_u,
                                                     const int* __restrict__ tot_m,
                                                     int* __restrict__ bb_m) {
  __shared__ int partial[1024];
  scan_inline(tot_u, bb_u, BU_BKTS, partial);
  __syncthreads();
  scan_inline(tot_m, bb_m, BM_BKTS, partial);
}

// ---------------------------------------------------------------------------
// K3: partition pass, LDS cursors only. rec = (src << 7) | dstlow.
// ---------------------------------------------------------------------------
__global__ __launch_bounds__(256) void part_k(const int* __restrict__ uidx,
                                              const int* __restrict__ midx,
                                              const int* __restrict__ C_u,
                                              const int* __restrict__ C_m,
                                              const int* __restrict__ bb_u,
                                              const int* __restrict__ bb_m,
                                              int* __restrict__ rec_u,
                                              int* __restrict__ rec_m) {
  __shared__ int cur[NBKT];
  for (int i = threadIdx.x; i < BU_BKTS; i += 256)
    cur[i] = bb_u[i] + C_u[(size_t)blockIdx.x * BU_BKTS + i];
  for (int i = threadIdx.x; i < BM_BKTS; i += 256)
    cur[BU_BKTS + i] = bb_m[i] + C_m[(size_t)blockIdx.x * BM_BKTS + i];
  __syncthreads();
  const int base = blockIdx.x * CHUNK;
  const int lim = min(base + CHUNK, NE);
  for (int e = base + threadIdx.x; e < lim; e += 256) {
    const int u = uidx[e];
    const int m = midx[e];
    const int pu = atomicAdd(&cur[u >> 7], 1);
    rec_u[pu] = (m << 7) | (u & (BDST - 1));
    const int pm = atomicAdd(&cur[BU_BKTS + (m >> 7)], 1);
    rec_m[pm] = (u << 7) | (m & (BDST - 1));
  }
}

// ---------------------------------------------------------------------------
// K4: per-bucket counting sort -> per-node CSR (adj + rowp). LDS atomics only.
// ---------------------------------------------------------------------------
__global__ __launch_bounds__(256) void sort_k(const int* __restrict__ rec_m,
                                              const int* __restrict__ rec_u,
                                              const int* __restrict__ bb_m,
                                              const int* __restrict__ bb_u,
                                              int* __restrict__ adj_m,
                                              int* __restrict__ adj_u,
                                              int* __restrict__ rowp_m,
                                              int* __restrict__ rowp_u) {
  __shared__ int cnt[BDST];
  __shared__ int off[BDST];
  __shared__ int tmp[BDST];
  const bool is_m = (blockIdx.x < BM_BKTS);
  const int bkt = is_m ? blockIdx.x : blockIdx.x - BM_BKTS;
  const int* recs = is_m ? rec_m : rec_u;
  const int* bb   = is_m ? bb_m : bb_u;
  int* adj  = is_m ? adj_m : adj_u;
  int* rowp = is_m ? rowp_m : rowp_u;
  const int nDst = is_m ? NM : NU;
  const int tid = threadIdx.x;

  for (int i = tid; i < BDST; i += 256) cnt[i] = 0;
  __syncthreads();
  const int rbeg = bb[bkt], rend = bb[bkt + 1];
  for (int j = rbeg + tid; j < rend; j += 256)
    atomicAdd(&cnt[recs[j] & (BDST - 1)], 1);
  __syncthreads();

  if (tid < BDST) tmp[tid] = cnt[tid];
  __syncthreads();
  for (int o = 1; o < BDST; o <<= 1) {
    int v = 0;
    if (tid < BDST && tid >= o) v = tmp[tid - o];
    __syncthreads();
    if (tid < BDST && tid >= o) tmp[tid] += v;
    __syncthreads();
  }
  if (tid < BDST) off[tid] = (tid == 0) ? 0 : tmp[tid - 1];
  __syncthreads();

  if (tid < BDST) {
    const int node = bkt * BDST + tid;
    if (node < nDst) rowp[node] = rbeg + off[tid];
  }
  if (blockIdx.x == 0 && tid == 0) rowp_m[NM] = NE;
  if (blockIdx.x == BM_BKTS && tid == 0) rowp_u[NU] = NE;

  if (tid < BDST) cnt[tid] = 0;
  __syncthreads();
  for (int j = rbeg + tid; j < rend; j += 256) {
    const int q = recs[j];
    const int dl = q & (BDST - 1);
    const int pos = atomicAdd(&cnt[dl], 1);
    adj[rbeg + off[dl] + pos] = q >> 7;
  }
}

// ---------------------------------------------------------------------------
// bf16 CSR gather-aggregate (layer 1), uint2: 16 lanes/row, 4 rows/wave-load.
// ---------------------------------------------------------------------------
__device__ __forceinline__ void agg_node16(const uint2* __restrict__ x2,
                                           const int* __restrict__ rowp,
                                           const int* __restrict__ adj,
                                           uint2* __restrict__ mean_h2,
                                           int node, int g, int q) {
  const int beg = rowp[node];
  const int end = rowp[node + 1];
  float a0 = 0.f, a1 = 0.f, a2 = 0.f, a3 = 0.f;
  int j = beg;
  for (; j + 16 <= end; j += 16) {
    const int e0 = adj[j + g];
    const int e1 = adj[j + 4 + g];
    const int e2 = adj[j + 8 + g];
    const int e3 = adj[j + 12 + g];
    const uint2 p0 = x2[(size_t)e0 * 16 + q];
    const uint2 p1 = x2[(size_t)e1 * 16 + q];
    const uint2 p2 = x2[(size_t)e2 * 16 + q];
    const uint2 p3 = x2[(size_t)e3 * 16 + q];
    a0 += (bflo(p0.x) + bflo(p1.x)) + (bflo(p2.x) + bflo(p3.x));
    a1 += (bfhi(p0.x) + bfhi(p1.x)) + (bfhi(p2.x) + bfhi(p3.x));
    a2 += (bflo(p0.y) + bflo(p1.y)) + (bflo(p2.y) + bflo(p3.y));
    a3 += (bfhi(p0.y) + bfhi(p1.y)) + (bfhi(p2.y) + bfhi(p3.y));
  }
  for (; j + 4 <= end; j += 4) {
    const int e = adj[j + g];
    const uint2 p = x2[(size_t)e * 16 + q];
    a0 += bflo(p.x); a1 += bfhi(p.x); a2 += bflo(p.y); a3 += bfhi(p.y);
  }
  if (j < end && g < end - j) {          // remainder 1..3 edges
    const int e = adj[j + g];
    const uint2 p = x2[(size_t)e * 16 + q];
    a0 += bflo(p.x); a1 += bfhi(p.x); a2 += bflo(p.y); a3 += bfhi(p.y);
  }
  a0 += __shfl_xor(a0, 16); a1 += __shfl_xor(a1, 16);
  a2 += __shfl_xor(a2, 16); a3 += __shfl_xor(a3, 16);
  a0 += __shfl_xor(a0, 32); a1 += __shfl_xor(a1, 32);
  a2 += __shfl_xor(a2, 32); a3 += __shfl_xor(a3, 32);
  if (g == 0) {
    const float inv = 1.0f / fmaxf((float)(end - beg), 1.0f);
    uint2 o;
    o.x = (uint_t)f2bf(a0 * inv) | ((uint_t)f2bf(a1 * inv) << 16);
    o.y = (uint_t)f2bf(a2 * inv) | ((uint_t)f2bf(a3 * inv) << 16);
    mean_h2[(size_t)node * 16 + q] = o;
  }
}

__global__ __launch_bounds__(256) void csr_both_h(const uint2* __restrict__ xu2,
                                                  const uint2* __restrict__ xm2,
                                                  const int* __restrict__ rowp_u,
                                                  const int* __restrict__ rowp_m,
                                                  const int* __restrict__ adj_u,
                                                  const int* __restrict__ adj_m,
                                                  uint2* __restrict__ mean_u2,
                                                  uint2* __restrict__ mean_m2) {
  const int lane = threadIdx.x & 63;
  const int g = lane >> 4;              // edge group 0..3
  const int q = lane & 15;              // uint2 position within row
  const int wid  = (blockIdx.x * blockDim.x + threadIdx.x) >> 6;
  const int W    = (gridDim.x * blockDim.x) >> 6;
  const int WM   = W / 3;
  if (wid < WM) {
    for (int node = wid; node < NM; node += WM)
      agg_node16(xu2, rowp_m, adj_m, mean_m2, node, g, q);
  } else {
    const int uw = wid - WM, UW = W - WM;
    for (int node = uw; node < NU; node += UW)
      agg_node16(xm2, rowp_u, adj_u, mean_u2, node, g, q);
  }
}

// ---------------------------------------------------------------------------
// uint8 CSR gather-aggregate (layer 2): 8 lanes/row (uint2 = 8 feats),
// 8 rows per wave-load, EXACT integer sums in packed 16-bit fields
// (deg*255 <= ~31K << 65536). Dequant once per node: mean = sum * s / deg.
// ---------------------------------------------------------------------------
__device__ __forceinline__ void agg_node8q(const uint2* __restrict__ xq,
                                           const int* __restrict__ rowp,
                                           const int* __restrict__ adj,
                                           uint4* __restrict__ mean_h4,
                                           float s, int node, int g, int q) {
  const int beg = rowp[node];
  const int end = rowp[node + 1];
  uint_t accA = 0, accB = 0, accC = 0, accD = 0;  // two 16-bit sums each
  int j = beg;
  for (; j + 16 <= end; j += 16) {
    const int e0 = adj[j + g];
    const int e1 = adj[j + 8 + g];
    const uint2 p0 = xq[(size_t)e0 * 8 + q];
    const uint2 p1 = xq[(size_t)e1 * 8 + q];
    accA += (p0.x & 0x00FF00FFu) + (p1.x & 0x00FF00FFu);
    accB += ((p0.x >> 8) & 0x00FF00FFu) + ((p1.x >> 8) & 0x00FF00FFu);
    accC += (p0.y & 0x00FF00FFu) + (p1.y & 0x00FF00FFu);
    accD += ((p0.y >> 8) & 0x00FF00FFu) + ((p1.y >> 8) & 0x00FF00FFu);
  }
  for (; j + 8 <= end; j += 8) {
    const int e = adj[j + g];
    const uint2 p = xq[(size_t)e * 8 + q];
    accA += p.x & 0x00FF00FFu;
    accB += (p.x >> 8) & 0x00FF00FFu;
    accC += p.y & 0x00FF00FFu;
    accD += (p.y >> 8) & 0x00FF00FFu;
  }
  if (j < end && g < end - j) {          // remainder 1..7 edges
    const int e = adj[j + g];
    const uint2 p = xq[(size_t)e * 8 + q];
    accA += p.x & 0x00FF00FFu;
    accB += (p.x >> 8) & 0x00FF00FFu;
    accC += p.y & 0x00FF00FFu;
    accD += (p.y >> 8) & 0x00FF00FFu;
  }
  // cross-group reduce over 8 groups (lane bits 3,4,5); fields stay < 2^16
  accA += (uint_t)__shfl_xor((int)accA, 8);
  accB += (uint_t)__shfl_xor((int)accB, 8);
  accC += (uint_t)__shfl_xor((int)accC, 8);
  accD += (uint_t)__shfl_xor((int)accD, 8);
  accA += (uint_t)__shfl_xor((int)accA, 16);
  accB += (uint_t)__shfl_xor((int)accB, 16);
  accC += (uint_t)__shfl_xor((int)accC, 16);
  accD += (uint_t)__shfl_xor((int)accD, 16);
  accA += (uint_t)__shfl_xor((int)accA, 32);
  accB += (uint_t)__shfl_xor((int)accB, 32);
  accC += (uint_t)__shfl_xor((int)accC, 32);
  accD += (uint_t)__shfl_xor((int)accD, 32);
  if (g == 0) {
    const float inv = s / fmaxf((float)(end - beg), 1.0f);
    // byte k of row = feature q*8+k: accA={f0,f2} accB={f1,f3} accC={f4,f6} accD={f5,f7}
    const float f0 = (float)(accA & 0xFFFFu) * inv;
    const float f1 = (float)(accB & 0xFFFFu) * inv;
    const float f2 = (float)(accA >> 16) * inv;
    const float f3 = (float)(accB >> 16) * inv;
    const float f4 = (float)(accC & 0xFFFFu) * inv;
    const float f5 = (float)(accD & 0xFFFFu) * inv;
    const float f6 = (float)(accC >> 16) * inv;
    const float f7 = (float)(accD >> 16) * inv;
    uint4 o;
    o.x = (uint_t)f2bf(f0) | ((uint_t)f2bf(f1) << 16);
    o.y = (uint_t)f2bf(f2) | ((uint_t)f2bf(f3) << 16);
    o.z = (uint_t)f2bf(f4) | ((uint_t)f2bf(f5) << 16);
    o.w = (uint_t)f2bf(f6) | ((uint_t)f2bf(f7) << 16);
    mean_h4[(size_t)node * 8 + q] = o;
  }
}

__global__ __launch_bounds__(256) void csr_both_q(const uint2* __restrict__ uq2,
                                                  const uint2* __restrict__ mq2,
                                                  const int* __restrict__ rowp_u,
                                                  const int* __restrict__ rowp_m,
                                                  const int* __restrict__ adj_u,
                                                  const int* __restrict__ adj_m,
                                                  uint4* __restrict__ mean_u4,
                                                  uint4* __restrict__ mean_m4,
                                                  const uint_t* __restrict__ gmax) {
  const float s_u = __uint_as_float(gmax[0]) * (1.0f / 255.0f);  // scale of u1_q
  const float s_m = __uint_as_float(gmax[1]) * (1.0f / 255.0f);  // scale of m1_q
  const int lane = threadIdx.x & 63;
  const int g = lane >> 3;              // edge group 0..7
  const int q = lane & 7;               // uint2 position within 64B row
  const int wid  = (blockIdx.x * blockDim.x + threadIdx.x) >> 6;
  const int W    = (gridDim.x * blockDim.x) >> 6;
  const int WM   = W / 3;
  if (wid < WM) {                       // movie dst gather USER sources (u1_q)
    for (int node = wid; node < NM; node += WM)
      agg_node8q(uq2, rowp_m, adj_m, mean_m4, s_u, node, g, q);
  } else {                              // user dst gather MOVIE sources (m1_q)
    const int uw = wid - WM, UW = W - WM;
    for (int node = uw; node < NU; node += UW)
      agg_node8q(mq2, rowp_u, adj_u, mean_u4, s_m, node, g, q);
  }
}

// ---------------------------------------------------------------------------
// quantize u1/m1 (bf16, >=0 after relu) to uint8 with step max/255.
// ---------------------------------------------------------------------------
__global__ __launch_bounds__(256) void quant_k(const uint4* __restrict__ u1h4,
                                               const uint4* __restrict__ m1h4,
                                               const uint_t* __restrict__ gmax,
                                               uint2* __restrict__ u1q2,
                                               uint2* __restrict__ m1q2) {
  const float qs_u = 255.0f / fmaxf(__uint_as_float(gmax[0]), 1e-20f);
  const float qs_m = 255.0f / fmaxf(__uint_as_float(gmax[1]), 1e-20f);
  const int n_u = NU * D / 8, n_m = NM * D / 8;
  const int stride = gridDim.x * blockDim.x;
  for (int i = blockIdx.x * blockDim.x + threadIdx.x; i < n_u + n_m; i += stride) {
    const bool isu = (i < n_u);
    const uint4 v = isu ? u1h4[i] : m1h4[i - n_u];
    const float qs = isu ? qs_u : qs_m;
    uint_t b0 = (uint_t)fminf(rintf(bflo(v.x) * qs), 255.f);
    uint_t b1 = (uint_t)fminf(rintf(bfhi(v.x) * qs), 255.f);
    uint_t b2 = (uint_t)fminf(rintf(bflo(v.y) * qs), 255.f);
    uint_t b3 = (uint_t)fminf(rintf(bfhi(v.y) * qs), 255.f);
    uint_t b4 = (uint_t)fminf(rintf(bflo(v.z) * qs), 255.f);
    uint_t b5 = (uint_t)fminf(rintf(bfhi(v.z) * qs), 255.f);
    uint_t b6 = (uint_t)fminf(rintf(bflo(v.w) * qs), 255.f);
    uint_t b7 = (uint_t)fminf(rintf(bfhi(v.w) * qs), 255.f);
    uint2 o;
    o.x = b0 | (b1 << 8) | (b2 << 16) | (b3 << 24);
    o.y = b4 | (b5 << 8) | (b6 << 16) | (b7 << 24);
    if (isu) u1q2[i] = o;
    else     m1q2[i - n_u] = o;
  }
}

// ---------------------------------------------------------------------------
// MFMA node transform: out = [relu]( mean @ Wl + b + x @ Wr )
// mode 1 additionally tracks max(out) per relation into gmax[0]=user, [1]=movie.
// ---------------------------------------------------------------------------
__global__ __launch_bounds__(256) void node_mfma_k(
    const ushort_t* __restrict__ mean_u, const ushort_t* __restrict__ mean_m,
    const ushort_t* __restrict__ xu_h,   const ushort_t* __restrict__ xm_h,
    const ushort_t* __restrict__ fragL_um, const ushort_t* __restrict__ fragR_um,
    const ushort_t* __restrict__ fragL_mu, const ushort_t* __restrict__ fragR_mu,
    const float* __restrict__ b_um, const float* __restrict__ b_mu,
    float* __restrict__ outf_u, float* __restrict__ outf_m,
    ushort_t* __restrict__ outh_u, ushort_t* __restrict__ outh_m,
    uint_t* __restrict__ gmax, int mode) {
  const int lane = threadIdx.x & 63;
  const int wid  = (blockIdx.x * blockDim.x + threadIdx.x) >> 6;
  const int W    = (gridDim.x * blockDim.x) >> 6;
  const int WM   = W / 3;

  const ushort_t *mean, *xh, *fL, *fR;
  const float* bias;
  float* outf;
  ushort_t* outh;
  int nt, t0, tstride, gidx;
  if (wid < WM) {               // movies: relation user->movie
    mean = mean_m; xh = xm_h; fL = fragL_um; fR = fragR_um; bias = b_um;
    outf = outf_m; outh = outh_m; nt = NM / 16; t0 = wid; tstride = WM; gidx = 1;
  } else {                      // users: relation movie->user
    mean = mean_u; xh = xu_h; fL = fragL_mu; fR = fragR_mu; bias = b_mu;
    outf = outf_u; outh = outh_u; nt = NU / 16; t0 = wid - WM; tstride = W - WM; gidx = 0;
  }

  short8_t bl[4][2], br[4][2];
#pragma unroll
  for (int t = 0; t < 4; ++t)
#pragma unroll
    for (int h = 0; h < 2; ++h) {
      bl[t][h] = *(const short8_t*)&fL[(size_t)((t * 2 + h) * 64 + lane) * 8];
      br[t][h] = *(const short8_t*)&fR[(size_t)((t * 2 + h) * 64 + lane) * 8];
    }
  const int colb = lane & 15;
  const int kq = lane >> 4;
  float bv[4];
#pragma unroll
  for (int t = 0; t < 4; ++t) bv[t] = bias[t * 16 + colb];

  float lmax = 0.f;
  for (int tile = t0; tile < nt; tile += tstride) {
    const int base = tile * 16;
    const ushort_t* mrow = mean + (size_t)(base + colb) * D + kq * 8;
    const ushort_t* xrow = xh   + (size_t)(base + colb) * D + kq * 8;
    const short8_t am0 = *(const short8_t*)(mrow);
    const short8_t am1 = *(const short8_t*)(mrow + 32);
    const short8_t ax0 = *(const short8_t*)(xrow);
    const short8_t ax1 = *(const short8_t*)(xrow + 32);
#pragma unroll
    for (int t = 0; t < 4; ++t) {
      f32x4_t acc = {bv[t], bv[t], bv[t], bv[t]};
      acc = __builtin_amdgcn_mfma_f32_16x16x32_bf16(am0, bl[t][0], acc, 0, 0, 0);
      acc = __builtin_amdgcn_mfma_f32_16x16x32_bf16(am1, bl[t][1], acc, 0, 0, 0);
      acc = __builtin_amdgcn_mfma_f32_16x16x32_bf16(ax0, br[t][0], acc, 0, 0, 0);
      acc = __builtin_amdgcn_mfma_f32_16x16x32_bf16(ax1, br[t][1], acc, 0, 0, 0);
      const int col = t * 16 + colb;
#pragma unroll
      for (int j = 0; j < 4; ++j) {
        const int node = base + kq * 4 + j;
        if (mode) {
          const float r = fmaxf(acc[j], 0.f);
          lmax = fmaxf(lmax, r);
          outh[(size_t)node * D + col] = f2bf(r);
        } else {
          outf[(size_t)node * D + col] = acc[j];
        }
      }
    }
  }
  if (mode) {
    // wave-reduce max, then one atomic per wave (bits of non-neg float are
    // order-preserving under unsigned compare)
    lmax = fmaxf(lmax, __shfl_xor(lmax, 1));
    lmax = fmaxf(lmax, __shfl_xor(lmax, 2));
    lmax = fmaxf(lmax, __shfl_xor(lmax, 4));
    lmax = fmaxf(lmax, __shfl_xor(lmax, 8));
    lmax = fmaxf(lmax, __shfl_xor(lmax, 16));
    lmax = fmaxf(lmax, __shfl_xor(lmax, 32));
    if (lane == 0) atomicMax(&gmax[gidx], __float_as_uint(lmax));
  }
}

// ---------------------------------------------------------------------------
extern "C" void kernel_launch(void* const* d_in, const int* in_sizes, int n_in,
                              void* d_out, int out_size, void* d_ws, size_t ws_size,
                              hipStream_t stream) {
  const float* x_user  = (const float*)d_in[0];
  const float* x_movie = (const float*)d_in[1];
  const float* Wl1_um = (const float*)d_in[2];
  const float* Wr1_um = (const float*)d_in[3];
  const float* b1_um  = (const float*)d_in[4];
  const float* Wl1_mu = (const float*)d_in[5];
  const float* Wr1_mu = (const float*)d_in[6];
  const float* b1_mu  = (const float*)d_in[7];
  const float* Wl2_um = (const float*)d_in[8];
  const float* Wr2_um = (const float*)d_in[9];
  const float* b2_um  = (const float*)d_in[10];
  const float* Wl2_mu = (const float*)d_in[11];
  const float* Wr2_mu = (const float*)d_in[12];
  const float* b2_mu  = (const float*)d_in[13];
  const int* uidx = (const int*)d_in[14];
  const int* midx = (const int*)d_in[15];

  // ---- workspace layout. Aliasing:
  //   rec_* (32 MB, dead after sort_k)  -> inside u1_h+m1_h (38.4 MB)
  //   C_*   (2.4 MB, dead after part_k) -> inside mean_u (25.6 MB)
  char* ws = (char*)d_ws;
  ushort_t* mean_u = (ushort_t*)ws; ws += (size_t)NU * D * sizeof(ushort_t); // 25.6 MB
  ushort_t* mean_m = (ushort_t*)ws; ws += (size_t)NM * D * sizeof(ushort_t); // 12.8 MB
  ushort_t* xu_h = (ushort_t*)ws;   ws += (size_t)NU * D * sizeof(ushort_t); // 25.6 MB
  ushort_t* xm_h = (ushort_t*)ws;   ws += (size_t)NM * D * sizeof(ushort_t); // 12.8 MB
  ushort_t* u1_h = (ushort_t*)ws;   ws += (size_t)NU * D * sizeof(ushort_t); // 25.6 MB
  ushort_t* m1_h = (ushort_t*)ws;   ws += (size_t)NM * D * sizeof(ushort_t); // 12.8 MB
  int* adj_u  = (int*)ws;           ws += (size_t)NE * sizeof(int);          // 16 MB
  int* adj_m  = (int*)ws;           ws += (size_t)NE * sizeof(int);          // 16 MB
  int* rowp_u = (int*)ws;           ws += ((size_t)NU + 1) * sizeof(int);
  int* rowp_m = (int*)ws;           ws += ((size_t)NM + 1) * sizeof(int);
  int* tot_u  = (int*)ws;           ws += (size_t)BU_BKTS * sizeof(int);
  int* tot_m  = (int*)ws;           ws += (size_t)BM_BKTS * sizeof(int);
  int* bb_u   = (int*)ws;           ws += ((size_t)BU_BKTS + 1) * sizeof(int);
  int* bb_m   = (int*)ws;           ws += ((size_t)BM_BKTS + 1) * sizeof(int);
  ushort_t* fragW = (ushort_t*)ws;  ws += (size_t)8 * 512 * 8 * sizeof(ushort_t); // 64 KB
  uchar_t* u1_q = (uchar_t*)ws;     ws += (size_t)NU * D;                     // 12.8 MB
  uchar_t* m1_q = (uchar_t*)ws;     ws += (size_t)NM * D;                     // 6.4 MB
  uint_t* gmax = (uint_t*)ws;       ws += 2 * sizeof(uint_t);

  int* rec_u = (int*)u1_h;                        // 16 MB \ inside u1_h+m1_h
  int* rec_m = rec_u + NE;                        // 16 MB /
  int* C_u   = (int*)mean_u;                      // 1.6 MB \ inside mean_u
  int* C_m   = C_u + (size_t)NBLK * BU_BKTS;      // 0.8 MB /

  float* u2 = (float*)d_out;
  float* m2 = (float*)d_out + (size_t)NU * D;

  const dim3 blk(256);

  // ---- bf16 casts + weight swizzle + CSR build ----
  hipMemsetAsync(gmax, 0, 2 * sizeof(uint_t), stream);
  cast_k<<<2048, blk, 0, stream>>>(x_user, x_movie, xu_h, xm_h);
  wprep_k<<<16, blk, 0, stream>>>(Wl1_um, Wr1_um, Wl1_mu, Wr1_mu,
                                  Wl2_um, Wr2_um, Wl2_mu, Wr2_mu, fragW);
  hist_k<<<NBLK, blk, 0, stream>>>(uidx, midx, C_u, C_m);
  colscan_k<<<(NBKT + 255) / 256, blk, 0, stream>>>(C_u, C_m, tot_u, tot_m);
  bucketscan_k<<<1, 1024, 0, stream>>>(tot_u, bb_u, tot_m, bb_m);
  part_k<<<NBLK, blk, 0, stream>>>(uidx, midx, C_u, C_m, bb_u, bb_m, rec_u, rec_m);
  sort_k<<<NBKT, blk, 0, stream>>>(rec_m, rec_u, bb_m, bb_u,
                                   adj_m, adj_u, rowp_m, rowp_u);

  // ---- layer 1 (relu, outputs bf16 u1_h/m1_h + per-relation max) ----
  csr_both_h<<<3072, blk, 0, stream>>>((const uint2*)xu_h, (const uint2*)xm_h,
                                       rowp_u, rowp_m, adj_u, adj_m,
                                       (uint2*)mean_u, (uint2*)mean_m);
  node_mfma_k<<<1024, blk, 0, stream>>>(mean_u, mean_m, xu_h, xm_h,
                                        fragW + 0 * 4096, fragW + 1 * 4096,
                                        fragW + 2 * 4096, fragW + 3 * 4096,
                                        b1_um, b1_mu,
                                        nullptr, nullptr, u1_h, m1_h, gmax, 1);

  // ---- quantize layer-1 outputs to uint8 ----
  quant_k<<<2048, blk, 0, stream>>>((const uint4*)u1_h, (const uint4*)m1_h,
                                    gmax, (uint2*)u1_q, (uint2*)m1_q);

  // ---- layer 2 (uint8 gather, no activation, writes f32 d_out) ----
  csr_both_q<<<3072, blk, 0, stream>>>((const uint2*)u1_q, (const uint2*)m1_q,
                                       rowp_u, rowp_m, adj_u, adj_m,
                                       (uint4*)mean_u, (uint4*)mean_m, gmax);
  node_mfma_k<<<1024, blk, 0, stream>>>(mean_u, mean_m, u1_h, m1_h,
                                        fragW + 4 * 4096, fragW + 5 * 4096,
                                        fragW + 6 * 4096, fragW + 7 * 4096,
                                        b2_um, b2_mu,
                                        u2, m2, nullptr, nullptr, gmax, 0);
}

// Round 11
// 606.168 us; speedup vs baseline: 1.1235x; 1.1235x over previous
//
#include <hip/hip_runtime.h>

#define NU 200000
#define NM 100000
#define NE 4000000
#define D  64

#define BDST 128                           // destinations per bucket (dst >> 7)
#define BU_BKTS ((NU + BDST - 1) / BDST)   // 1563 user buckets
#define BM_BKTS ((NM + BDST - 1) / BDST)   // 782 movie buckets
#define NBKT (BU_BKTS + BM_BKTS)           // 2345
#define NBLK 256                           // partition blocking
#define CHUNK ((NE + NBLK - 1) / NBLK)     // 15625

typedef unsigned int uint_t;
typedef unsigned short ushort_t;
typedef __attribute__((ext_vector_type(8))) short short8_t;   // 8 bf16 (4 VGPR)
typedef __attribute__((ext_vector_type(4))) float f32x4_t;    // MFMA acc

__device__ __forceinline__ ushort_t f2bf(float f) {            // RNE f32->bf16
  uint_t u = __float_as_uint(f);
  return (ushort_t)((u + 0x7FFFu + ((u >> 16) & 1u)) >> 16);
}
__device__ __forceinline__ float bflo(uint_t p) { return __uint_as_float(p << 16); }
__device__ __forceinline__ float bfhi(uint_t p) { return __uint_as_float(p & 0xFFFF0000u); }

// ---------------------------------------------------------------------------
// fused: blocks 0-15 swizzle the 8 weight matrices into MFMA B-fragments,
// then all blocks cast x_user/x_movie to bf16 (float4 -> ushort4).
// frag[mat][t][h][lane][j] = bf16( W[h*32 + (lane>>4)*8 + j][t*16 + (lane&15)] )
// ---------------------------------------------------------------------------
__global__ __launch_bounds__(256) void cast_wprep_k(
    const float* __restrict__ xu, const float* __restrict__ xm,
    ushort_t* __restrict__ xu_h, ushort_t* __restrict__ xm_h,
    const float* __restrict__ W0, const float* __restrict__ W1,
    const float* __restrict__ W2, const float* __restrict__ W3,
    const float* __restrict__ W4, const float* __restrict__ W5,
    const float* __restrict__ W6, const float* __restrict__ W7,
    ushort_t* __restrict__ frag) {
  if (blockIdx.x < 16) {
    const int idx = blockIdx.x * 256 + threadIdx.x;   // 8 mats * 512 entries
    const int lane = idx & 63;
    const int h = (idx >> 6) & 1;
    const int t = (idx >> 7) & 3;
    const int mat = idx >> 9;
    const float* W = mat == 0 ? W0 : mat == 1 ? W1 : mat == 2 ? W2 : mat == 3 ? W3
                   : mat == 4 ? W4 : mat == 5 ? W5 : mat == 6 ? W6 : W7;
    const int col = t * 16 + (lane & 15);
    const int kb = h * 32 + (lane >> 4) * 8;
#pragma unroll
    for (int j = 0; j < 8; ++j)
      frag[(size_t)idx * 8 + j] = f2bf(W[(kb + j) * D + col]);
  }
  const int n_u = NU * D / 4, n_m = NM * D / 4;
  const int stride = gridDim.x * blockDim.x;
  for (int i = blockIdx.x * blockDim.x + threadIdx.x; i < n_u + n_m; i += stride) {
    const bool isu = (i < n_u);
    const float4 v = isu ? ((const float4*)xu)[i] : ((const float4*)xm)[i - n_u];
    ushort4 o;
    o.x = f2bf(v.x); o.y = f2bf(v.y); o.z = f2bf(v.z); o.w = f2bf(v.w);
    if (isu) ((ushort4*)xu_h)[i] = o;
    else     ((ushort4*)xm_h)[i - n_u] = o;
  }
}

// ---------------------------------------------------------------------------
// K1: per-block bucket histogram (both directions), LDS atomics only.
// ---------------------------------------------------------------------------
__global__ __launch_bounds__(256) void hist_k(const int* __restrict__ uidx,
                                              const int* __restrict__ midx,
                                              int* __restrict__ C_u,
                                              int* __restrict__ C_m) {
  __shared__ int h[NBKT];
  for (int i = threadIdx.x; i < NBKT; i += 256) h[i] = 0;
  __syncthreads();
  const int base = blockIdx.x * CHUNK;
  const int lim = min(base + CHUNK, NE);
  for (int e = base + threadIdx.x; e < lim; e += 256) {
    atomicAdd(&h[uidx[e] >> 7], 1);
    atomicAdd(&h[BU_BKTS + (midx[e] >> 7)], 1);
  }
  __syncthreads();
  for (int i = threadIdx.x; i < BU_BKTS; i += 256) C_u[(size_t)blockIdx.x * BU_BKTS + i] = h[i];
  for (int i = threadIdx.x; i < BM_BKTS; i += 256) C_m[(size_t)blockIdx.x * BM_BKTS + i] = h[BU_BKTS + i];
}

// ---------------------------------------------------------------------------
// K2a: per-bucket exclusive prefix over the 256 blocks; emit bucket totals.
// ---------------------------------------------------------------------------
__global__ __launch_bounds__(256) void colscan_k(int* __restrict__ C_u,
                                                 int* __restrict__ C_m,
                                                 int* __restrict__ tot_u,
                                                 int* __restrict__ tot_m) {
  const int t = blockIdx.x * blockDim.x + threadIdx.x;
  if (t < BU_BKTS) {
    int run = 0;
    for (int blk = 0; blk < NBLK; ++blk) {
      const size_t idx = (size_t)blk * BU_BKTS + t;
      const int v = C_u[idx];
      C_u[idx] = run;
      run += v;
    }
    tot_u[t] = run;
  } else if (t < NBKT) {
    const int b = t - BU_BKTS;
    int run = 0;
    for (int blk = 0; blk < NBLK; ++blk) {
      const size_t idx = (size_t)blk * BM_BKTS + b;
      const int v = C_m[idx];
      C_m[idx] = run;
      run += v;
    }
    tot_m[b] = run;
  }
}

// ---------------------------------------------------------------------------
// K2b: single-block exclusive scans of bucket totals -> bucket bases.
// ---------------------------------------------------------------------------
__device__ void scan_inline(const int* __restrict__ in, int* __restrict__ out,
                            int n, int* partial) {
  const int tid = threadIdx.x;
  const int chunk = (n + 1023) / 1024;
  const int s = tid * chunk;
  const int e = min(s + chunk, n);
  int sum = 0;
  for (int i = s; i < e; ++i) sum += in[i];
  partial[tid] = sum;
  __syncthreads();
  for (int off = 1; off < 1024; off <<= 1) {
    int v = (tid >= off) ? partial[tid - off] : 0;
    __syncthreads();
    if (tid >= off) partial[tid] += v;
    __syncthreads();
  }
  int run = (tid == 0) ? 0 : partial[tid - 1];
  for (int i = s; i < e; ++i) {
    out[i] = run;
    run += in[i];
  }
  if (tid == 1023) out[n] = partial[1023];
}

__global__ __launch_bounds__(1024) void bucketscan_k(const int* __restrict__ tot_u,
                                                     int* __restrict__ bb_u,
                                                     const int* __restrict__ tot_m,
                                                     int* __restrict__ bb_m) {
  __shared__ int partial[1024];
  scan_inline(tot_u, bb_u, BU_BKTS, partial);
  __syncthreads();
  scan_inline(tot_m, bb_m, BM_BKTS, partial);
}

// ---------------------------------------------------------------------------
// K3: partition pass, LDS cursors only. rec = (src << 7) | dstlow.
// ---------------------------------------------------------------------------
__global__ __launch_bounds__(256) void part_k(const int* __restrict__ uidx,
                                              const int* __restrict__ midx,
                                              const int* __restrict__ C_u,
                                              const int* __restrict__ C_m,
                                              const int* __restrict__ bb_u,
                                              const int* __restrict__ bb_m,
                                              int* __restrict__ rec_u,
                                              int* __restrict__ rec_m) {
  __shared__ int cur[NBKT];
  for (int i = threadIdx.x; i < BU_BKTS; i += 256)
    cur[i] = bb_u[i] + C_u[(size_t)blockIdx.x * BU_BKTS + i];
  for (int i = threadIdx.x; i < BM_BKTS; i += 256)
    cur[BU_BKTS + i] = bb_m[i] + C_m[(size_t)blockIdx.x * BM_BKTS + i];
  __syncthreads();
  const int base = blockIdx.x * CHUNK;
  const int lim = min(base + CHUNK, NE);
  for (int e = base + threadIdx.x; e < lim; e += 256) {
    const int u = uidx[e];
    const int m = midx[e];
    const int pu = atomicAdd(&cur[u >> 7], 1);
    rec_u[pu] = (m << 7) | (u & (BDST - 1));
    const int pm = atomicAdd(&cur[BU_BKTS + (m >> 7)], 1);
    rec_m[pm] = (u << 7) | (m & (BDST - 1));
  }
}

// ---------------------------------------------------------------------------
// K4: per-bucket counting sort -> per-node CSR (adj + rowp). LDS atomics only.
// ---------------------------------------------------------------------------
__global__ __launch_bounds__(256) void sort_k(const int* __restrict__ rec_m,
                                              const int* __restrict__ rec_u,
                                              const int* __restrict__ bb_m,
                                              const int* __restrict__ bb_u,
                                              int* __restrict__ adj_m,
                                              int* __restrict__ adj_u,
                                              int* __restrict__ rowp_m,
                                              int* __restrict__ rowp_u) {
  __shared__ int cnt[BDST];
  __shared__ int off[BDST];
  __shared__ int tmp[BDST];
  const bool is_m = (blockIdx.x < BM_BKTS);
  const int bkt = is_m ? blockIdx.x : blockIdx.x - BM_BKTS;
  const int* recs = is_m ? rec_m : rec_u;
  const int* bb   = is_m ? bb_m : bb_u;
  int* adj  = is_m ? adj_m : adj_u;
  int* rowp = is_m ? rowp_m : rowp_u;
  const int nDst = is_m ? NM : NU;
  const int tid = threadIdx.x;

  for (int i = tid; i < BDST; i += 256) cnt[i] = 0;
  __syncthreads();
  const int rbeg = bb[bkt], rend = bb[bkt + 1];
  for (int j = rbeg + tid; j < rend; j += 256)
    atomicAdd(&cnt[recs[j] & (BDST - 1)], 1);
  __syncthreads();

  if (tid < BDST) tmp[tid] = cnt[tid];
  __syncthreads();
  for (int o = 1; o < BDST; o <<= 1) {
    int v = 0;
    if (tid < BDST && tid >= o) v = tmp[tid - o];
    __syncthreads();
    if (tid < BDST && tid >= o) tmp[tid] += v;
    __syncthreads();
  }
  if (tid < BDST) off[tid] = (tid == 0) ? 0 : tmp[tid - 1];
  __syncthreads();

  if (tid < BDST) {
    const int node = bkt * BDST + tid;
    if (node < nDst) rowp[node] = rbeg + off[tid];
  }
  if (blockIdx.x == 0 && tid == 0) rowp_m[NM] = NE;
  if (blockIdx.x == BM_BKTS && tid == 0) rowp_u[NU] = NE;

  if (tid < BDST) cnt[tid] = 0;
  __syncthreads();
  for (int j = rbeg + tid; j < rend; j += 256) {
    const int q = recs[j];
    const int dl = q & (BDST - 1);
    const int pos = atomicAdd(&cnt[dl], 1);
    adj[rbeg + off[dl] + pos] = q >> 7;
  }
}

// ---------------------------------------------------------------------------
// bf16 CSR gather-aggregate, uint2: 16 lanes/row (8 B/lane = 128 B row =
// exactly one L2 line), 4 rows per wave-load, 16 edges in flight.
// ---------------------------------------------------------------------------
__device__ __forceinline__ void agg_node16(const uint2* __restrict__ x2,
                                           const int* __restrict__ rowp,
                                           const int* __restrict__ adj,
                                           uint2* __restrict__ mean_h2,
                                           int node, int g, int q) {
  const int beg = rowp[node];
  const int end = rowp[node + 1];
  float a0 = 0.f, a1 = 0.f, a2 = 0.f, a3 = 0.f;
  int j = beg;
  for (; j + 16 <= end; j += 16) {
    const int e0 = adj[j + g];
    const int e1 = adj[j + 4 + g];
    const int e2 = adj[j + 8 + g];
    const int e3 = adj[j + 12 + g];
    const uint2 p0 = x2[(size_t)e0 * 16 + q];
    const uint2 p1 = x2[(size_t)e1 * 16 + q];
    const uint2 p2 = x2[(size_t)e2 * 16 + q];
    const uint2 p3 = x2[(size_t)e3 * 16 + q];
    a0 += (bflo(p0.x) + bflo(p1.x)) + (bflo(p2.x) + bflo(p3.x));
    a1 += (bfhi(p0.x) + bfhi(p1.x)) + (bfhi(p2.x) + bfhi(p3.x));
    a2 += (bflo(p0.y) + bflo(p1.y)) + (bflo(p2.y) + bflo(p3.y));
    a3 += (bfhi(p0.y) + bfhi(p1.y)) + (bfhi(p2.y) + bfhi(p3.y));
  }
  for (; j + 4 <= end; j += 4) {
    const int e = adj[j + g];
    const uint2 p = x2[(size_t)e * 16 + q];
    a0 += bflo(p.x); a1 += bfhi(p.x); a2 += bflo(p.y); a3 += bfhi(p.y);
  }
  if (j < end && g < end - j) {          // remainder 1..3 edges
    const int e = adj[j + g];
    const uint2 p = x2[(size_t)e * 16 + q];
    a0 += bflo(p.x); a1 += bfhi(p.x); a2 += bflo(p.y); a3 += bfhi(p.y);
  }
  a0 += __shfl_xor(a0, 16); a1 += __shfl_xor(a1, 16);
  a2 += __shfl_xor(a2, 16); a3 += __shfl_xor(a3, 16);
  a0 += __shfl_xor(a0, 32); a1 += __shfl_xor(a1, 32);
  a2 += __shfl_xor(a2, 32); a3 += __shfl_xor(a3, 32);
  if (g == 0) {
    const float inv = 1.0f / fmaxf((float)(end - beg), 1.0f);
    uint2 o;
    o.x = (uint_t)f2bf(a0 * inv) | ((uint_t)f2bf(a1 * inv) << 16);
    o.y = (uint_t)f2bf(a2 * inv) | ((uint_t)f2bf(a3 * inv) << 16);
    mean_h2[(size_t)node * 16 + q] = o;
  }
}

__global__ __launch_bounds__(256) void csr_both_h(const uint2* __restrict__ xu2,
                                                  const uint2* __restrict__ xm2,
                                                  const int* __restrict__ rowp_u,
                                                  const int* __restrict__ rowp_m,
                                                  const int* __restrict__ adj_u,
                                                  const int* __restrict__ adj_m,
                                                  uint2* __restrict__ mean_u2,
                                                  uint2* __restrict__ mean_m2) {
  const int lane = threadIdx.x & 63;
  const int g = lane >> 4;              // edge group 0..3
  const int q = lane & 15;              // uint2 position within row
  const int wid  = (blockIdx.x * blockDim.x + threadIdx.x) >> 6;
  const int W    = (gridDim.x * blockDim.x) >> 6;
  const int WM   = W / 3;
  if (wid < WM) {
    for (int node = wid; node < NM; node += WM)
      agg_node16(xu2, rowp_m, adj_m, mean_m2, node, g, q);
  } else {
    const int uw = wid - WM, UW = W - WM;
    for (int node = uw; node < NU; node += UW)
      agg_node16(xm2, rowp_u, adj_u, mean_u2, node, g, q);
  }
}

// ---------------------------------------------------------------------------
// MFMA node transform: out = [relu]( mean @ Wl + b + x @ Wr )
// wave handles 16 nodes x 64 cols = 16 x mfma_f32_16x16x32_bf16.
// mode 1: relu + bf16 out; mode 0: f32 out (d_out).
// ---------------------------------------------------------------------------
__global__ __launch_bounds__(256) void node_mfma_k(
    const ushort_t* __restrict__ mean_u, const ushort_t* __restrict__ mean_m,
    const ushort_t* __restrict__ xu_h,   const ushort_t* __restrict__ xm_h,
    const ushort_t* __restrict__ fragL_um, const ushort_t* __restrict__ fragR_um,
    const ushort_t* __restrict__ fragL_mu, const ushort_t* __restrict__ fragR_mu,
    const float* __restrict__ b_um, const float* __restrict__ b_mu,
    float* __restrict__ outf_u, float* __restrict__ outf_m,
    ushort_t* __restrict__ outh_u, ushort_t* __restrict__ outh_m, int mode) {
  const int lane = threadIdx.x & 63;
  const int wid  = (blockIdx.x * blockDim.x + threadIdx.x) >> 6;
  const int W    = (gridDim.x * blockDim.x) >> 6;
  const int WM   = W / 3;

  const ushort_t *mean, *xh, *fL, *fR;
  const float* bias;
  float* outf;
  ushort_t* outh;
  int nt, t0, tstride;
  if (wid < WM) {               // movies: relation user->movie
    mean = mean_m; xh = xm_h; fL = fragL_um; fR = fragR_um; bias = b_um;
    outf = outf_m; outh = outh_m; nt = NM / 16; t0 = wid; tstride = WM;
  } else {                      // users: relation movie->user
    mean = mean_u; xh = xu_h; fL = fragL_mu; fR = fragR_mu; bias = b_mu;
    outf = outf_u; outh = outh_u; nt = NU / 16; t0 = wid - WM; tstride = W - WM;
  }

  short8_t bl[4][2], br[4][2];
#pragma unroll
  for (int t = 0; t < 4; ++t)
#pragma unroll
    for (int h = 0; h < 2; ++h) {
      bl[t][h] = *(const short8_t*)&fL[(size_t)((t * 2 + h) * 64 + lane) * 8];
      br[t][h] = *(const short8_t*)&fR[(size_t)((t * 2 + h) * 64 + lane) * 8];
    }
  const int colb = lane & 15;
  const int kq = lane >> 4;
  float bv[4];
#pragma unroll
  for (int t = 0; t < 4; ++t) bv[t] = bias[t * 16 + colb];

  for (int tile = t0; tile < nt; tile += tstride) {
    const int base = tile * 16;
    const ushort_t* mrow = mean + (size_t)(base + colb) * D + kq * 8;
    const ushort_t* xrow = xh   + (size_t)(base + colb) * D + kq * 8;
    const short8_t am0 = *(const short8_t*)(mrow);
    const short8_t am1 = *(const short8_t*)(mrow + 32);
    const short8_t ax0 = *(const short8_t*)(xrow);
    const short8_t ax1 = *(const short8_t*)(xrow + 32);
#pragma unroll
    for (int t = 0; t < 4; ++t) {
      f32x4_t acc = {bv[t], bv[t], bv[t], bv[t]};
      acc = __builtin_amdgcn_mfma_f32_16x16x32_bf16(am0, bl[t][0], acc, 0, 0, 0);
      acc = __builtin_amdgcn_mfma_f32_16x16x32_bf16(am1, bl[t][1], acc, 0, 0, 0);
      acc = __builtin_amdgcn_mfma_f32_16x16x32_bf16(ax0, br[t][0], acc, 0, 0, 0);
      acc = __builtin_amdgcn_mfma_f32_16x16x32_bf16(ax1, br[t][1], acc, 0, 0, 0);
      const int col = t * 16 + colb;
#pragma unroll
      for (int j = 0; j < 4; ++j) {
        const int node = base + kq * 4 + j;
        if (mode) {
          outh[(size_t)node * D + col] = f2bf(fmaxf(acc[j], 0.f));
        } else {
          outf[(size_t)node * D + col] = acc[j];
        }
      }
    }
  }
}

// ---------------------------------------------------------------------------
extern "C" void kernel_launch(void* const* d_in, const int* in_sizes, int n_in,
                              void* d_out, int out_size, void* d_ws, size_t ws_size,
                              hipStream_t stream) {
  const float* x_user  = (const float*)d_in[0];
  const float* x_movie = (const float*)d_in[1];
  const float* Wl1_um = (const float*)d_in[2];
  const float* Wr1_um = (const float*)d_in[3];
  const float* b1_um  = (const float*)d_in[4];
  const float* Wl1_mu = (const float*)d_in[5];
  const float* Wr1_mu = (const float*)d_in[6];
  const float* b1_mu  = (const float*)d_in[7];
  const float* Wl2_um = (const float*)d_in[8];
  const float* Wr2_um = (const float*)d_in[9];
  const float* b2_um  = (const float*)d_in[10];
  const float* Wl2_mu = (const float*)d_in[11];
  const float* Wr2_mu = (const float*)d_in[12];
  const float* b2_mu  = (const float*)d_in[13];
  const int* uidx = (const int*)d_in[14];
  const int* midx = (const int*)d_in[15];

  // ---- workspace layout. Aliasing:
  //   rec_* (32 MB, dead after sort_k)  -> inside u1_h+m1_h (38.4 MB)
  //   C_*   (2.4 MB, dead after part_k) -> inside mean_u (25.6 MB)
  char* ws = (char*)d_ws;
  ushort_t* mean_u = (ushort_t*)ws; ws += (size_t)NU * D * sizeof(ushort_t); // 25.6 MB
  ushort_t* mean_m = (ushort_t*)ws; ws += (size_t)NM * D * sizeof(ushort_t); // 12.8 MB
  ushort_t* xu_h = (ushort_t*)ws;   ws += (size_t)NU * D * sizeof(ushort_t); // 25.6 MB
  ushort_t* xm_h = (ushort_t*)ws;   ws += (size_t)NM * D * sizeof(ushort_t); // 12.8 MB
  ushort_t* u1_h = (ushort_t*)ws;   ws += (size_t)NU * D * sizeof(ushort_t); // 25.6 MB
  ushort_t* m1_h = (ushort_t*)ws;   ws += (size_t)NM * D * sizeof(ushort_t); // 12.8 MB
  int* adj_u  = (int*)ws;           ws += (size_t)NE * sizeof(int);          // 16 MB
  int* adj_m  = (int*)ws;           ws += (size_t)NE * sizeof(int);          // 16 MB
  int* rowp_u = (int*)ws;           ws += ((size_t)NU + 1) * sizeof(int);
  int* rowp_m = (int*)ws;           ws += ((size_t)NM + 1) * sizeof(int);
  int* tot_u  = (int*)ws;           ws += (size_t)BU_BKTS * sizeof(int);
  int* tot_m  = (int*)ws;           ws += (size_t)BM_BKTS * sizeof(int);
  int* bb_u   = (int*)ws;           ws += ((size_t)BU_BKTS + 1) * sizeof(int);
  int* bb_m   = (int*)ws;           ws += ((size_t)BM_BKTS + 1) * sizeof(int);
  ushort_t* fragW = (ushort_t*)ws;  ws += (size_t)8 * 512 * 8 * sizeof(ushort_t); // 64 KB

  int* rec_u = (int*)u1_h;                        // 16 MB \ inside u1_h+m1_h
  int* rec_m = rec_u + NE;                        // 16 MB /
  int* C_u   = (int*)mean_u;                      // 1.6 MB \ inside mean_u
  int* C_m   = C_u + (size_t)NBLK * BU_BKTS;      // 0.8 MB /

  float* u2 = (float*)d_out;
  float* m2 = (float*)d_out + (size_t)NU * D;

  const dim3 blk(256);

  // ---- bf16 casts + weight swizzle (fused) + CSR build ----
  cast_wprep_k<<<2048, blk, 0, stream>>>(x_user, x_movie, xu_h, xm_h,
                                         Wl1_um, Wr1_um, Wl1_mu, Wr1_mu,
                                         Wl2_um, Wr2_um, Wl2_mu, Wr2_mu, fragW);
  hist_k<<<NBLK, blk, 0, stream>>>(uidx, midx, C_u, C_m);
  colscan_k<<<(NBKT + 255) / 256, blk, 0, stream>>>(C_u, C_m, tot_u, tot_m);
  bucketscan_k<<<1, 1024, 0, stream>>>(tot_u, bb_u, tot_m, bb_m);
  part_k<<<NBLK, blk, 0, stream>>>(uidx, midx, C_u, C_m, bb_u, bb_m, rec_u, rec_m);
  sort_k<<<NBKT, blk, 0, stream>>>(rec_m, rec_u, bb_m, bb_u,
                                   adj_m, adj_u, rowp_m, rowp_u);

  // ---- layer 1 (relu, outputs bf16 u1_h/m1_h) ----
  csr_both_h<<<3072, blk, 0, stream>>>((const uint2*)xu_h, (const uint2*)xm_h,
                                       rowp_u, rowp_m, adj_u, adj_m,
                                       (uint2*)mean_u, (uint2*)mean_m);
  node_mfma_k<<<1024, blk, 0, stream>>>(mean_u, mean_m, xu_h, xm_h,
                                        fragW + 0 * 4096, fragW + 1 * 4096,
                                        fragW + 2 * 4096, fragW + 3 * 4096,
                                        b1_um, b1_mu,
                                        nullptr, nullptr, u1_h, m1_h, 1);

  // ---- layer 2 (no activation, writes f32 d_out) ----
  csr_both_h<<<3072, blk, 0, stream>>>((const uint2*)u1_h, (const uint2*)m1_h,
                                       rowp_u, rowp_m, adj_u, adj_m,
                                       (uint2*)mean_u, (uint2*)mean_m);
  node_mfma_k<<<1024, blk, 0, stream>>>(mean_u, mean_m, u1_h, m1_h,
                                        fragW + 4 * 4096, fragW + 5 * 4096,
                                        fragW + 6 * 4096, fragW + 7 * 4096,
                                        b2_um, b2_mu,
                                        u2, m2, nullptr, nullptr, 0);
}